// Round 9
// baseline (275.262 us; speedup 1.0000x reference)
//
#include <hip/hip_runtime.h>
#include <stdint.h>

typedef unsigned short u16;
typedef __attribute__((ext_vector_type(4))) float f32x4;
typedef __attribute__((ext_vector_type(4))) uint32_t u32x4;
typedef __attribute__((ext_vector_type(8))) __bf16 bf16x8;

#if __has_builtin(__builtin_amdgcn_exp2f)
#define EXP2(x) __builtin_amdgcn_exp2f(x)
#else
#define EXP2(x) exp2f(x)
#endif

static __device__ __forceinline__ u16 f2bf(float f) {
    union { float f; uint32_t i; } v; v.f = f;
    return (u16)((v.i + 0x7FFFu + ((v.i >> 16) & 1u)) >> 16);
}
// packed f32x2 -> bf16x2 (RNE), single VALU op
static __device__ __forceinline__ uint32_t cvtpk(float lo, float hi) {
    uint32_t r;
    asm("v_cvt_pk_bf16_f32 %0, %1, %2" : "=v"(r) : "v"(lo), "v"(hi));
    return r;
}

// async global->LDS DMA, 16 B per lane; lds dest = wave-uniform base + lane*16
static __device__ __forceinline__ void gl2lds16(const u16* g, u16* lds) {
    __builtin_amdgcn_global_load_lds(
        (const __attribute__((address_space(1))) void*)g,
        (__attribute__((address_space(3))) void*)lds, 16, 0, 0);
}

// ---------------------------------------------------------------- fused prologue
// blocks [0,3072): XA = x @ A^T + fused x->bf16 cast
// blocks [3072,3328): f32->bf16 weight cast
// blocks [3328,3840): mask all-ones tile flags
// r8 (resubmitted after infra failure): XA branch rescheduled for static ILP
// (in-order issue!). Dot phase interleaves 2 independent FMA chains (2x2cy
// issue = 4cy FMA latency -> full VALU feed); butterfly reduction hoisted +
// interleaved (8 independent shuffles per level instead of 8 serial 6-level
// chains). Reduction order per r is UNCHANGED -> bit-identical results.
// Was: 51us at 18% HBM / 10% VALU (latency-bound, ~75% dependency stall).
struct PrepArgs {
    const float* x[3]; const float* A[3]; float* o[3]; u16* xb[3];   // xa
    const float* wsrc[4]; u16* wdst[4];                              // cast
    const int* mask; int* flags;                                     // flags
};

__global__ __launch_bounds__(256)
void prep_kernel(PrepArgs a) {
    const int bid = blockIdx.x;
    const int tid = threadIdx.x;

    if (bid < 3072) {
        // ---- XA + x cast ----
        const int z = bid >> 10;
        const int row = (bid & 1023) * 4 + (tid >> 6);
        const int lane = tid & 63;
        const float* xr = a.x[z] + (size_t)row * 1024 + lane * 16;
        float xv[16];
#pragma unroll
        for (int j = 0; j < 4; ++j) *(float4*)&xv[j * 4] = *(const float4*)(xr + j * 4);
        {
            u16 ob[16];
#pragma unroll
            for (int j = 0; j < 16; ++j) ob[j] = f2bf(xv[j]);
            u16* dp = a.xb[z] + (size_t)row * 1024 + lane * 16;
            *(uint4*)dp = *(const uint4*)&ob[0];
            *(uint4*)(dp + 8) = *(const uint4*)&ob[8];
        }
        float acc8[8];
        // dot phase: 2 r's interleaved (independent chains -> static ILP)
#pragma unroll
        for (int rp = 0; rp < 4; ++rp) {
            const float* a0 = a.A[z] + (size_t)(2 * rp) * 1024 + lane * 16;
            const float* a1 = a0 + 1024;
            float av0[16], av1[16];
#pragma unroll
            for (int j = 0; j < 4; ++j) {
                *(float4*)&av0[j * 4] = *(const float4*)(a0 + j * 4);
                *(float4*)&av1[j * 4] = *(const float4*)(a1 + j * 4);
            }
            float s0 = 0.f, s1 = 0.f;
#pragma unroll
            for (int j = 0; j < 16; ++j) { s0 += xv[j] * av0[j]; s1 += xv[j] * av1[j]; }
            acc8[2 * rp] = s0;
            acc8[2 * rp + 1] = s1;
        }
        // butterfly reduce: 6 levels x 8 independent shuffles (latency overlapped);
        // per-r reduction order identical to the serial version.
#pragma unroll
        for (int off = 1; off < 64; off <<= 1) {
#pragma unroll
            for (int r = 0; r < 8; ++r) acc8[r] += __shfl_xor(acc8[r], off, 64);
        }
        if (lane == 0) {
            float* op = a.o[z] + (size_t)row * 8;
            *(float4*)op = *(const float4*)&acc8[0];
            *(float4*)(op + 4) = *(const float4*)&acc8[4];
        }
    } else if (bid < 3328) {
        // ---- weight cast ----
        const int b2 = bid - 3072;
        const int arr = b2 >> 6, boff = b2 & 63;
        const float* s = a.wsrc[arr] + (size_t)boff * 16384;
        u16* d = a.wdst[arr] + (size_t)boff * 16384;
#pragma unroll
        for (int i = 0; i < 8; ++i) {
            int c = tid + i * 256;
            float4 f0 = *(const float4*)(s + c * 8);
            float4 f1 = *(const float4*)(s + c * 8 + 4);
            u16 o[8];
            o[0] = f2bf(f0.x); o[1] = f2bf(f0.y); o[2] = f2bf(f0.z); o[3] = f2bf(f0.w);
            o[4] = f2bf(f1.x); o[5] = f2bf(f1.y); o[6] = f2bf(f1.z); o[7] = f2bf(f1.w);
            *(uint4*)(d + c * 8) = *(const uint4*)o;
        }
    } else {
        // ---- mask flags ----
        const int b3 = bid - 3328;
        const int qb = b3 & 15, kt = b3 >> 4;
        int ok = 1;
#pragma unroll
        for (int i = 0; i < 8; ++i) {
            int c = tid + i * 256;
            int row = c >> 4, cg = c & 15;
            int4 m4 = *(const int4*)&a.mask[(size_t)(qb * 128 + row) * 2048 + kt * 64 + cg * 4];
            ok &= (m4.x != 0) & (m4.y != 0) & (m4.z != 0) & (m4.w != 0);
        }
        int wall = __all(ok) ? 1 : 0;
        __shared__ int red[4];
        if ((tid & 63) == 0) red[tid >> 6] = wall;
        __syncthreads();
        if (tid == 0) a.flags[qb * 32 + kt] = red[0] & red[1] & red[2] & red[3];
    }
}

// ---------------------------------------------------------------- GEMM  C = (X·W^T + bias + 2·XA·Bm^T) * oscale
// m97-style: BK=64, global_load_lds width-16 staging, XOR-swizzled source columns.
struct GemmPtrs { const u16* X; const u16* W; const float* bias; const float* XA; const float* Bm; void* out; int transT; float oscale; };
struct GemmArgs { GemmPtrs p[3]; };

#define LST 136  // straight epilogue staging row stride (u16)
#define LTT 72   // transposed epilogue staging row stride (u16)

template <int WMT, int WNT, int LORA>
__global__ __launch_bounds__(256, 2)
void gemm_kernel(GemmArgs args) {
    constexpr int BM = WMT * 32, BN = WNT * 32;
    constexpr int MBLK = 4096 / BM;
    constexpr int IPA = BM / 32;
    constexpr int IPB = BN / 32;
    __shared__ alignas(16) u16 smem[(BM + BN) * 64];
    u16* As = smem;            // [BM][64]
    u16* Bs = smem + BM * 64;  // [BN][64]

    const GemmPtrs gp = args.p[blockIdx.z];
    const int tid = threadIdx.x;
    const int lane = tid & 63, wave = tid >> 6;
    const int wm = wave >> 1, wn = wave & 1;
    const int l15 = lane & 15, l4 = lane >> 4;
    const int id = blockIdx.x;
    const int m0 = (id % MBLK) * BM, n0 = (id / MBLK) * BN;

    const int srow = lane >> 3;
    const int scol = ((lane & 7) ^ srow) * 8;
    const u16* gA[IPA];
    const u16* gB[IPB];
#pragma unroll
    for (int i = 0; i < IPA; ++i) {
        int q = wave * IPA + i;
        gA[i] = gp.X + (size_t)(m0 + q * 8 + srow) * 1024 + scol;
    }
#pragma unroll
    for (int i = 0; i < IPB; ++i) {
        int q = wave * IPB + i;
        gB[i] = gp.W + (size_t)(n0 + q * 8 + srow) * 1024 + scol;
    }

    const f32x4 fz = {0.f, 0.f, 0.f, 0.f};
    f32x4 acc[WMT][WNT];
#pragma unroll
    for (int i = 0; i < WMT; ++i)
#pragma unroll
        for (int j = 0; j < WNT; ++j) acc[i][j] = fz;

    const int sw = l15 & 7;
    for (int kb = 0; kb < 16; ++kb) {
        __syncthreads();
#pragma unroll
        for (int i = 0; i < IPA; ++i)
            gl2lds16(gA[i] + kb * 64, &As[(wave * IPA + i) * 512]);
#pragma unroll
        for (int i = 0; i < IPB; ++i)
            gl2lds16(gB[i] + kb * 64, &Bs[(wave * IPB + i) * 512]);
        __syncthreads();
#pragma unroll
        for (int kk2 = 0; kk2 < 2; ++kk2) {
            bf16x8 af[WMT], bfr[WNT];
#pragma unroll
            for (int mt = 0; mt < WMT; ++mt) {
                int x = wm * (WMT * 16) + mt * 16 + l15;
                af[mt] = *(const bf16x8*)&As[x * 64 + (((kk2 * 4 + l4) ^ sw) * 8)];
            }
#pragma unroll
            for (int nt = 0; nt < WNT; ++nt) {
                int y = wn * (WNT * 16) + nt * 16 + l15;
                bfr[nt] = *(const bf16x8*)&Bs[y * 64 + (((kk2 * 4 + l4) ^ sw) * 8)];
            }
#pragma unroll
            for (int mt = 0; mt < WMT; ++mt)
#pragma unroll
                for (int nt = 0; nt < WNT; ++nt)
                    acc[mt][nt] = __builtin_amdgcn_mfma_f32_16x16x32_bf16(af[mt], bfr[nt], acc[mt][nt], 0, 0, 0);
        }
    }

    if constexpr (LORA) {
        // ---- fold (bias + 2*XA·Bm^T) and oscale into acc (BM==BN==128) ----
        __syncthreads();
        float* XAs = (float*)smem;
        float* Bms = (float*)(smem + BM * 64);
        {
            int rr = tid >> 1, hf = (tid & 1) * 4;
            *(float4*)&XAs[rr * 8 + hf] = *(const float4*)&gp.XA[(size_t)(m0 + rr) * 8 + hf];
            if (tid < 128) {
                *(float4*)&Bms[tid * 8]     = *(const float4*)&gp.Bm[(size_t)(n0 + tid) * 8];
                *(float4*)&Bms[tid * 8 + 4] = *(const float4*)&gp.Bm[(size_t)(n0 + tid) * 8 + 4];
            }
        }
        __syncthreads();
        const float osc = gp.oscale;
        float bmv[WNT][8], bsv[WNT];
#pragma unroll
        for (int nt = 0; nt < WNT; ++nt) {
            int nloc = wn * 64 + nt * 16 + l15;
            bsv[nt] = gp.bias[n0 + nloc];
#pragma unroll
            for (int q8 = 0; q8 < 8; ++q8) bmv[nt][q8] = Bms[nloc * 8 + q8];
        }
#pragma unroll
        for (int mt = 0; mt < WMT; ++mt)
#pragma unroll
            for (int r = 0; r < 4; ++r) {
                int mloc = wm * 64 + mt * 16 + l4 * 4 + r;
                float xa8[8];
                *(float4*)&xa8[0] = *(const float4*)&XAs[mloc * 8];
                *(float4*)&xa8[4] = *(const float4*)&XAs[mloc * 8 + 4];
#pragma unroll
                for (int nt = 0; nt < WNT; ++nt) {
                    float lora = 0.f;
#pragma unroll
                    for (int q8 = 0; q8 < 8; ++q8) lora += xa8[q8] * bmv[nt][q8];
                    acc[mt][nt][r] = (acc[mt][nt][r] + bsv[nt] + 2.0f * lora) * osc;
                }
            }
        __syncthreads();

        u16* outp = (u16*)gp.out;
        const int bb = m0 >> 11;
        if (gp.transT) {
            // ---- transposed staging: store V plane as [h][d][t] ----
            u16* Lst = smem;   // [128 n][LTT]
#pragma unroll
            for (int ch = 0; ch < 2; ++ch) {
#pragma unroll
                for (int mt2 = 0; mt2 < 2; ++mt2) {
                    int mt = ch * 2 + mt2;
#pragma unroll
                    for (int nt = 0; nt < WNT; ++nt)
#pragma unroll
                        for (int r = 0; r < 4; ++r)
                            Lst[(wn * 64 + nt * 16 + l15) * LTT + wm * 32 + mt2 * 16 + l4 * 4 + r] =
                                f2bf(acc[mt][nt][r]);
                }
                __syncthreads();
#pragma unroll
                for (int j = 0; j < 4; ++j) {
                    int w = tid + j * 256;
                    int nl = w >> 3, seg = w & 7;
                    uint4 val = *(const uint4*)&Lst[nl * LTT + seg * 8];
                    int n = n0 + nl, hh = n >> 6, dd = n & 63;
                    int c0 = seg * 8;
                    int gm = m0 + (c0 >> 5) * 64 + ch * 32 + (c0 & 31);
                    int t = gm & 2047;
                    *(uint4*)&outp[(((size_t)(bb * 16 + hh)) * 64 + dd) * 2048 + t] = val;
                }
                __syncthreads();
            }
        } else {
            // ---- straight staging: [h][t][d] layout ----
            u16* Ls = smem;    // [64][LST]
#pragma unroll
            for (int ch = 0; ch < 2; ++ch) {
#pragma unroll
                for (int mt2 = 0; mt2 < 2; ++mt2) {
                    int mt = ch * 2 + mt2;
#pragma unroll
                    for (int nt = 0; nt < WNT; ++nt)
#pragma unroll
                        for (int r = 0; r < 4; ++r)
                            Ls[(wm * 32 + mt2 * 16 + l4 * 4 + r) * LST + wn * 64 + nt * 16 + l15] =
                                f2bf(acc[mt][nt][r]);
                }
                __syncthreads();
#pragma unroll
                for (int j = 0; j < 4; ++j) {
                    int w = tid + j * 256;
                    int lrow = w >> 4, seg = w & 15;
                    uint4 val = *(const uint4*)&Ls[lrow * LST + seg * 8];
                    int gm = m0 + (lrow >> 5) * 64 + ch * 32 + (lrow & 31);
                    int t = gm & 2047;
                    int n = n0 + seg * 8, hh = n >> 6, dd = n & 63;
                    *(uint4*)&outp[(((size_t)(bb * 16 + hh)) * 2048 + t) * 64 + dd] = val;
                }
                __syncthreads();
            }
        }
    } else {
        float* outp = (float*)gp.out;
#pragma unroll
        for (int mt = 0; mt < WMT; ++mt)
#pragma unroll
            for (int r = 0; r < 4; ++r) {
                int m = m0 + wm * (WMT * 16) + mt * 16 + l4 * 4 + r;
#pragma unroll
                for (int nt = 0; nt < WNT; ++nt) {
                    int n = n0 + wn * (WNT * 16) + nt * 16 + l15;
                    outp[(size_t)m * 1024 + n] = acc[mt][nt][r] + gp.bias[n];
                }
            }
    }
}

// ---------------------------------------------------------------- flash attention
// r2-verified structure (4 waves x 16 q-rows, 256 thr, 16 waves/CU). Swapped-QK^T
// with in-lane P via row-permuted K staging, K/V dbuf via global_load_lds with
// XOR chunk swizzle, 1 barrier/iter. p=exp2(s') -- constant softmax bias cancels
// in normalization (r7-verified).

__global__ __launch_bounds__(256, 4)
void attn_kernel(const u16* __restrict__ QKV, const int* __restrict__ mask,
                 const int* __restrict__ flags, u16* __restrict__ Xo) {
    const int qb = blockIdx.x >> 5;          // 0..31 (64-row q blocks)
    const int bh = blockIdx.x & 31;
    const int b = bh >> 4, h = bh & 15;
    const int tid = threadIdx.x;
    const int lane = tid & 63, wave = tid >> 6;
    const int l15 = lane & 15, l4 = lane >> 4;

    __shared__ alignas(16) u16 Ks[2][64 * 64];    // row-permuted + XOR-swizzled, dbuf
    __shared__ alignas(16) u16 Vts[2][64 * 64];   // [d][k-tile], XOR-swizzled, dbuf

    const size_t plane = (size_t)2 * 16 * 2048 * 64;
    const u16* Qg = QKV + (size_t)(b * 16 + h) * 2048 * 64;   // [t][d] (pre-scaled)
    const u16* Kg = Qg + plane;                                // [t][d]
    const u16* Vg = Kg + plane;                                // [d][t]

    const int srow = lane >> 3;
    const int scol = ((lane & 7) ^ srow) * 8;

    // per-lane staging source pointers (kt-invariant part)
    const u16* kbase[2];
    const u16* vbase[2];
#pragma unroll
    for (int i = 0; i < 2; ++i) {
        int qq = wave * 2 + i;
        // k-col feeding LDS row qq*8+srow (row permutation, see r1 header)
        int kc = 16 * (qq & 1) + 8 * (srow >> 2) + 4 * ((qq >> 1) & 1) + (srow & 3) + 32 * (qq >> 2);
        kbase[i] = Kg + (size_t)kc * 64 + scol;
        vbase[i] = Vg + (size_t)(qq * 8 + srow) * 2048 + scol;
    }

    // Q fragments in registers (wave owns 16 q-rows)
    bf16x8 qa[2];
#pragma unroll
    for (int kk2 = 0; kk2 < 2; ++kk2)
        qa[kk2] = *(const bf16x8*)&Qg[(size_t)(qb * 64 + wave * 16 + l15) * 64 + kk2 * 32 + l4 * 8];

    const f32x4 fz = {0.f, 0.f, 0.f, 0.f};
    f32x4 accO[4];
#pragma unroll
    for (int dt = 0; dt < 4; ++dt) accO[dt] = fz;
    float lsum = 0.f;

    // prologue: stage tile 0 into buffer 0
#pragma unroll
    for (int i = 0; i < 2; ++i) {
        int qq = wave * 2 + i;
        gl2lds16(kbase[i], &Ks[0][qq * 512]);
        gl2lds16(vbase[i], &Vts[0][qq * 512]);
    }
    __syncthreads();   // vmcnt drain: tile 0 landed

    for (int kt = 0; kt < 32; ++kt) {
        const u16* Kc = &Ks[kt & 1][0];
        const u16* Vc = &Vts[kt & 1][0];

        // issue next tile's DMA into the other buffer; latency hides under compute
        if (kt < 31) {
            u16* Kn = &Ks[(kt + 1) & 1][0];
            u16* Vn = &Vts[(kt + 1) & 1][0];
#pragma unroll
            for (int i = 0; i < 2; ++i) {
                int qq = wave * 2 + i;
                gl2lds16(kbase[i] + (size_t)(kt + 1) * 4096, &Kn[qq * 512]);
                gl2lds16(vbase[i] + (size_t)(kt + 1) * 64, &Vn[qq * 512]);
            }
        }

        // S^T = K Q^T: accS[j] col = q-row l15, row m -> k-col 8*l4+4*(j&1)+r+32*(j>>1)
        f32x4 accS[4];
#pragma unroll
        for (int j = 0; j < 4; ++j) accS[j] = fz;
#pragma unroll
        for (int kk2 = 0; kk2 < 2; ++kk2) {
            bf16x8 kf[4];
#pragma unroll
            for (int j = 0; j < 4; ++j)
                kf[j] = *(const bf16x8*)&Kc[(j * 16 + l15) * 64 + (((kk2 * 4 + l4) ^ (l15 & 7)) * 8)];
            __builtin_amdgcn_s_setprio(1);
#pragma unroll
            for (int j = 0; j < 4; ++j)
                accS[j] = __builtin_amdgcn_mfma_f32_16x16x32_bf16(kf[j], qa[kk2], accS[j], 0, 0, 0);
            __builtin_amdgcn_s_setprio(0);
        }

        if (flags[(qb >> 1) * 32 + kt] == 0) {
            int qrow = qb * 64 + wave * 16 + l15;
#pragma unroll
            for (int j = 0; j < 4; ++j)
#pragma unroll
                for (int r = 0; r < 4; ++r) {
                    int kcol = kt * 64 + 8 * l4 + 4 * (j & 1) + r + 32 * (j >> 1);
                    if (mask[(size_t)qrow * 2048 + kcol] == 0) accS[j][r] = -1e9f;
                }
        }

        // p = exp2(s'); constant softmax bias dropped (cancels in normalization)
        float part0 = 0.f, part1 = 0.f;
#pragma unroll
        for (int j = 0; j < 4; ++j)
#pragma unroll
            for (int r = 0; r < 4; ++r) {
                float p = EXP2(accS[j][r]);
                accS[j][r] = p;
                if (j & 1) part1 += p; else part0 += p;
            }
        lsum += part0 + part1;

        // PV A-fragment built fully in-lane: j0,j1 -> kk2=0 cols 8*l4+0..7; j2,j3 -> kk2=1
        u32x4 paw0, paw1;
        paw0[0] = cvtpk(accS[0][0], accS[0][1]); paw0[1] = cvtpk(accS[0][2], accS[0][3]);
        paw0[2] = cvtpk(accS[1][0], accS[1][1]); paw0[3] = cvtpk(accS[1][2], accS[1][3]);
        paw1[0] = cvtpk(accS[2][0], accS[2][1]); paw1[1] = cvtpk(accS[2][2], accS[2][3]);
        paw1[2] = cvtpk(accS[3][0], accS[3][1]); paw1[3] = cvtpk(accS[3][2], accS[3][3]);
        bf16x8 pa[2];
        pa[0] = __builtin_bit_cast(bf16x8, paw0);
        pa[1] = __builtin_bit_cast(bf16x8, paw1);

        // O += P V
#pragma unroll
        for (int kk2 = 0; kk2 < 2; ++kk2) {
            bf16x8 vf[4];
#pragma unroll
            for (int dt = 0; dt < 4; ++dt)
                vf[dt] = *(const bf16x8*)&Vc[(dt * 16 + l15) * 64 + (((kk2 * 4 + l4) ^ (l15 & 7)) * 8)];
            __builtin_amdgcn_s_setprio(1);
#pragma unroll
            for (int dt = 0; dt < 4; ++dt)
                accO[dt] = __builtin_amdgcn_mfma_f32_16x16x32_bf16(pa[kk2], vf[dt], accO[dt], 0, 0, 0);
            __builtin_amdgcn_s_setprio(0);
        }

        // single barrier per iteration: drains next tile's DMA (vmcnt(0)) and
        // guarantees all waves finished reading buf cur before it is overwritten
        __syncthreads();
    }

    // row totals: lane holds partial for q-row l15; reduce over the 4 l4 copies
    float tot = lsum;
    tot += __shfl_xor(tot, 16, 64);
    tot += __shfl_xor(tot, 32, 64);
    float inv[4];
#pragma unroll
    for (int r = 0; r < 4; ++r) inv[r] = 1.0f / __shfl(tot, l4 * 4 + r, 64);

    // LDS-staged coalesced output (reuse Ks[0]; XOR chunk swizzle)
    u16* Es = &Ks[0][0];
#pragma unroll
    for (int dt = 0; dt < 4; ++dt)
#pragma unroll
        for (int r = 0; r < 4; ++r) {
            int prow = wave * 16 + l4 * 4 + r;
            Es[prow * 64 + (((dt * 2 + (l15 >> 3)) ^ (prow & 7)) * 8) + (l15 & 7)] =
                f2bf(accO[dt][r] * inv[r]);
        }
    __syncthreads();
#pragma unroll
    for (int j = 0; j < 2; ++j) {
        int w = tid + j * 256;            // 512: 64 rows x 8 segs
        int row = w >> 3, seg = w & 7;
        uint4 val = *(const uint4*)&Es[row * 64 + ((seg ^ (row & 7)) * 8)];
        int t = qb * 64 + row;
        *(uint4*)&Xo[((size_t)(b * 2048 + t)) * 1024 + h * 64 + seg * 8] = val;
    }
}

// ---------------------------------------------------------------- launch
extern "C" void kernel_launch(void* const* d_in, const int* in_sizes, int n_in,
                              void* d_out, int out_size, void* d_ws, size_t ws_size,
                              hipStream_t stream) {
    const float* q    = (const float*)d_in[0];
    const float* k    = (const float*)d_in[1];
    const float* v    = (const float*)d_in[2];
    const int*   mask = (const int*)d_in[3];
    const float* Wq = (const float*)d_in[4];
    const float* bq = (const float*)d_in[5];
    const float* Aq = (const float*)d_in[6];
    const float* Bq = (const float*)d_in[7];
    const float* Wk = (const float*)d_in[8];
    const float* bk = (const float*)d_in[9];
    const float* Ak = (const float*)d_in[10];
    const float* Bk = (const float*)d_in[11];
    const float* Wv = (const float*)d_in[12];
    const float* bv = (const float*)d_in[13];
    const float* Av = (const float*)d_in[14];
    const float* Bv = (const float*)d_in[15];
    const float* Wo = (const float*)d_in[16];
    const float* bo = (const float*)d_in[17];

    char* ws = (char*)d_ws;
    u16*   QKV   = (u16*)ws;                    // Q,K: [b][h][t][d]; V: [b][h][d][t]
    u16*   qb16  = (u16*)(ws + 25165824);
    u16*   kb16  = (u16*)(ws + 33554432);
    u16*   vb16  = (u16*)(ws + 41943040);
    u16*   Wqb   = (u16*)(ws + 50331648);
    u16*   Wkb   = (u16*)(ws + 52428800);
    u16*   Wvb   = (u16*)(ws + 54525952);
    u16*   Wob   = (u16*)(ws + 56623104);
    float* XAbuf = (float*)(ws + 58720256);
    int*   flags = (int*)(ws + 59113472);
    u16*   Xbuf  = qb16;

    PrepArgs pa;
    pa.x[0] = q;  pa.x[1] = k;  pa.x[2] = v;
    pa.A[0] = Aq; pa.A[1] = Ak; pa.A[2] = Av;
    pa.o[0] = XAbuf; pa.o[1] = XAbuf + 32768; pa.o[2] = XAbuf + 65536;
    pa.xb[0] = qb16; pa.xb[1] = kb16; pa.xb[2] = vb16;
    pa.wsrc[0] = Wq; pa.wsrc[1] = Wk; pa.wsrc[2] = Wv; pa.wsrc[3] = Wo;
    pa.wdst[0] = Wqb; pa.wdst[1] = Wkb; pa.wdst[2] = Wvb; pa.wdst[3] = Wob;
    pa.mask = mask; pa.flags = flags;
    prep_kernel<<<dim3(3840), dim3(256), 0, stream>>>(pa);

    const float QSCALE = 0.1803368801f;   // 0.125 * log2(e)
    GemmArgs g1;
    g1.p[0] = GemmPtrs{qb16, Wqb, bq, XAbuf,         Bq, (void*)QKV,             0, QSCALE};
    g1.p[1] = GemmPtrs{kb16, Wkb, bk, XAbuf + 32768, Bk, (void*)(QKV + 4194304), 0, 1.0f};
    g1.p[2] = GemmPtrs{vb16, Wvb, bv, XAbuf + 65536, Bv, (void*)(QKV + 8388608), 1, 1.0f};
    gemm_kernel<4, 4, 1><<<dim3(256, 1, 3), dim3(256), 0, stream>>>(g1);

    attn_kernel<<<dim3(1024), dim3(256), 0, stream>>>(QKV, mask, flags, Xbuf);

    GemmArgs g2;
    g2.p[0] = GemmPtrs{Xbuf, Wob, bo, nullptr, nullptr, d_out, 0, 1.0f};
    g2.p[1] = g2.p[0];
    g2.p[2] = g2.p[0];
    gemm_kernel<2, 4, 0><<<dim3(512, 1, 1), dim3(256), 0, stream>>>(g2);
}

// Round 10
// 255.407 us; speedup vs baseline: 1.0777x; 1.0777x over previous
//
#include <hip/hip_runtime.h>
#include <stdint.h>

typedef unsigned short u16;
typedef __attribute__((ext_vector_type(4))) float f32x4;
typedef __attribute__((ext_vector_type(4))) uint32_t u32x4;
typedef __attribute__((ext_vector_type(8))) __bf16 bf16x8;

#if __has_builtin(__builtin_amdgcn_exp2f)
#define EXP2(x) __builtin_amdgcn_exp2f(x)
#else
#define EXP2(x) exp2f(x)
#endif

static __device__ __forceinline__ u16 f2bf(float f) {
    union { float f; uint32_t i; } v; v.f = f;
    return (u16)((v.i + 0x7FFFu + ((v.i >> 16) & 1u)) >> 16);
}
// packed f32x2 -> bf16x2 (RNE), single VALU op
static __device__ __forceinline__ uint32_t cvtpk(float lo, float hi) {
    uint32_t r;
    asm("v_cvt_pk_bf16_f32 %0, %1, %2" : "=v"(r) : "v"(lo), "v"(hi));
    return r;
}

// async global->LDS DMA, 16 B per lane; lds dest = wave-uniform base + lane*16
static __device__ __forceinline__ void gl2lds16(const u16* g, u16* lds) {
    __builtin_amdgcn_global_load_lds(
        (const __attribute__((address_space(1))) void*)g,
        (__attribute__((address_space(3))) void*)lds, 16, 0, 0);
}

// ---------------------------------------------------------------- fused prologue
// r10: XA computation REMOVED from prep (it resisted two rounds of latency
// optimization at 50+us with no saturated pipe). XA is now computed inside
// gemm1 via MFMA on the already-staged x fragments (see gemm_kernel). prep is
// now pure streaming: casts (x + W, 7 arrays), A fragment-pack, mask flags.
// blocks [0,1024): f32->bf16 casts  (x: 3x256 blocks, W: 4x64 blocks)
// blocks [1024,1536): mask all-ones tile flags
// blocks [1536,1539): A zero-padded bf16 fragment-pack (one block per z)
struct PrepArgs {
    const float* csrc[7]; u16* cdst[7];   // q,k,v,Wq,Wk,Wv,Wo
    const float* A[3]; u16* apk[3];       // A pack: [kb*2+kk2][lane][8] bf16
    const int* mask; int* flags;
};

__global__ __launch_bounds__(256)
void prep_kernel(PrepArgs a) {
    const int bid = blockIdx.x;
    const int tid = threadIdx.x;

    if (bid < 1024) {
        // ---- streaming f32 -> bf16 cast (16384 elems per block) ----
        int arr, boff;
        if (bid < 768) { arr = bid >> 8; boff = bid & 255; }
        else { int b2 = bid - 768; arr = 3 + (b2 >> 6); boff = b2 & 63; }
        const float* s = a.csrc[arr] + (size_t)boff * 16384;
        u16* d = a.cdst[arr] + (size_t)boff * 16384;
#pragma unroll
        for (int i = 0; i < 8; ++i) {
            int c = tid + i * 256;
            float4 f0 = *(const float4*)(s + c * 8);
            float4 f1 = *(const float4*)(s + c * 8 + 4);
            u16 o[8];
            o[0] = f2bf(f0.x); o[1] = f2bf(f0.y); o[2] = f2bf(f0.z); o[3] = f2bf(f0.w);
            o[4] = f2bf(f1.x); o[5] = f2bf(f1.y); o[6] = f2bf(f1.z); o[7] = f2bf(f1.w);
            *(uint4*)(d + c * 8) = *(const uint4*)o;
        }
    } else if (bid < 1536) {
        // ---- mask flags ----
        const int b3 = bid - 1024;
        const int qb = b3 & 15, kt = b3 >> 4;
        int ok = 1;
#pragma unroll
        for (int i = 0; i < 8; ++i) {
            int c = tid + i * 256;
            int row = c >> 4, cg = c & 15;
            int4 m4 = *(const int4*)&a.mask[(size_t)(qb * 128 + row) * 2048 + kt * 64 + cg * 4];
            ok &= (m4.x != 0) & (m4.y != 0) & (m4.z != 0) & (m4.w != 0);
        }
        int wall = __all(ok) ? 1 : 0;
        __shared__ int red[4];
        if ((tid & 63) == 0) red[tid >> 6] = wall;
        __syncthreads();
        if (tid == 0) a.flags[qb * 32 + kt] = red[0] & red[1] & red[2] & red[3];
    } else {
        // ---- A fragment-pack: apk[((kb*2+kk2)*64 + lane)*8 + j] =
        //      (l15<8) ? bf16(A[l15][kb*64 + kk2*32 + l4*8 + j]) : 0
        //      (zero-padded rows 8..15 so the XA MFMA's upper cols vanish) ----
        const int z = bid - 1536;
        const float* Az = a.A[z];
        u16* dp = a.apk[z];
#pragma unroll
        for (int i = 0; i < 8; ++i) {
            int pos = tid + i * 256;           // 2048 fragment chunks
            int lane2 = pos & 63;
            int l15_ = lane2 & 15, l4_ = lane2 >> 4;
            int kbkk = pos >> 6;
            int kcol = (kbkk >> 1) * 64 + (kbkk & 1) * 32 + l4_ * 8;
            u16 ob[8] = {0, 0, 0, 0, 0, 0, 0, 0};
            if (l15_ < 8) {
                float4 f0 = *(const float4*)&Az[(size_t)l15_ * 1024 + kcol];
                float4 f1 = *(const float4*)&Az[(size_t)l15_ * 1024 + kcol + 4];
                ob[0] = f2bf(f0.x); ob[1] = f2bf(f0.y); ob[2] = f2bf(f0.z); ob[3] = f2bf(f0.w);
                ob[4] = f2bf(f1.x); ob[5] = f2bf(f1.y); ob[6] = f2bf(f1.z); ob[7] = f2bf(f1.w);
            }
            *(uint4*)&dp[(size_t)pos * 8] = *(const uint4*)ob;
        }
    }
}

// ---------------------------------------------------------------- GEMM  C = (X·W^T + bias + 2·XA·Bm^T) * oscale
// m97-style: BK=64, global_load_lds width-16 staging, XOR-swizzled source columns.
// r10: LORA path computes XA = X·A^T IN-KERNEL via one extra MFMA per (kb,kk2,mt)
// reusing the already-loaded af fragments (A staged as packed bf16, rows 8..15
// zero). acc_xa is written to the XAs LDS region in the epilogue, replacing the
// former global XA load; downstream lora code unchanged.
struct GemmPtrs { const u16* X; const u16* W; const float* bias; const u16* Ap; const float* Bm; void* out; int transT; float oscale; };
struct GemmArgs { GemmPtrs p[3]; };

#define LST 136  // straight epilogue staging row stride (u16)
#define LTT 72   // transposed epilogue staging row stride (u16)

template <int WMT, int WNT, int LORA>
__global__ __launch_bounds__(256, 2)
void gemm_kernel(GemmArgs args) {
    constexpr int BM = WMT * 32, BN = WNT * 32;
    constexpr int MBLK = 4096 / BM;
    constexpr int IPA = BM / 32;
    constexpr int IPB = BN / 32;
    __shared__ alignas(16) u16 smem[(BM + BN) * 64];
    u16* As = smem;            // [BM][64]
    u16* Bs = smem + BM * 64;  // [BN][64]

    const GemmPtrs gp = args.p[blockIdx.z];
    const int tid = threadIdx.x;
    const int lane = tid & 63, wave = tid >> 6;
    const int wm = wave >> 1, wn = wave & 1;
    const int l15 = lane & 15, l4 = lane >> 4;
    const int id = blockIdx.x;
    const int m0 = (id % MBLK) * BM, n0 = (id / MBLK) * BN;

    const int srow = lane >> 3;
    const int scol = ((lane & 7) ^ srow) * 8;
    const u16* gA[IPA];
    const u16* gB[IPB];
#pragma unroll
    for (int i = 0; i < IPA; ++i) {
        int q = wave * IPA + i;
        gA[i] = gp.X + (size_t)(m0 + q * 8 + srow) * 1024 + scol;
    }
#pragma unroll
    for (int i = 0; i < IPB; ++i) {
        int q = wave * IPB + i;
        gB[i] = gp.W + (size_t)(n0 + q * 8 + srow) * 1024 + scol;
    }

    const f32x4 fz = {0.f, 0.f, 0.f, 0.f};
    f32x4 acc[WMT][WNT];
#pragma unroll
    for (int i = 0; i < WMT; ++i)
#pragma unroll
        for (int j = 0; j < WNT; ++j) acc[i][j] = fz;
    f32x4 acc_xa[WMT];
    if constexpr (LORA) {
#pragma unroll
        for (int i = 0; i < WMT; ++i) acc_xa[i] = fz;
    }

    const int sw = l15 & 7;
    for (int kb = 0; kb < 16; ++kb) {
        __syncthreads();
#pragma unroll
        for (int i = 0; i < IPA; ++i)
            gl2lds16(gA[i] + kb * 64, &As[(wave * IPA + i) * 512]);
#pragma unroll
        for (int i = 0; i < IPB; ++i)
            gl2lds16(gB[i] + kb * 64, &Bs[(wave * IPB + i) * 512]);
        __syncthreads();
#pragma unroll
        for (int kk2 = 0; kk2 < 2; ++kk2) {
            bf16x8 af[WMT], bfr[WNT];
#pragma unroll
            for (int mt = 0; mt < WMT; ++mt) {
                int x = wm * (WMT * 16) + mt * 16 + l15;
                af[mt] = *(const bf16x8*)&As[x * 64 + (((kk2 * 4 + l4) ^ sw) * 8)];
            }
#pragma unroll
            for (int nt = 0; nt < WNT; ++nt) {
                int y = wn * (WNT * 16) + nt * 16 + l15;
                bfr[nt] = *(const bf16x8*)&Bs[y * 64 + (((kk2 * 4 + l4) ^ sw) * 8)];
            }
#pragma unroll
            for (int mt = 0; mt < WMT; ++mt)
#pragma unroll
                for (int nt = 0; nt < WNT; ++nt)
                    acc[mt][nt] = __builtin_amdgcn_mfma_f32_16x16x32_bf16(af[mt], bfr[nt], acc[mt][nt], 0, 0, 0);
            if constexpr (LORA) {
                // XA: af holds x[m][k-chunk kk2*32+l4*8]; abf holds A[l15][same chunk]
                bf16x8 abf = *(const bf16x8*)&gp.Ap[(size_t)((kb * 2 + kk2) * 64 + lane) * 8];
#pragma unroll
                for (int mt = 0; mt < WMT; ++mt)
                    acc_xa[mt] = __builtin_amdgcn_mfma_f32_16x16x32_bf16(af[mt], abf, acc_xa[mt], 0, 0, 0);
            }
        }
    }

    if constexpr (LORA) {
        // ---- fold (bias + 2*XA·Bm^T) and oscale into acc (BM==BN==128) ----
        __syncthreads();
        float* XAs = (float*)smem;
        float* Bms = (float*)(smem + BM * 64);
        // store in-kernel XA fragments: C-layout row=wm*64+mt*16+l4*4+r, col=l15
        // (wn==1 waves hold a redundant copy; rows 8..15 of A are zero-padded)
        if (wn == 0 && l15 < 8) {
#pragma unroll
            for (int mt = 0; mt < WMT; ++mt)
#pragma unroll
                for (int r = 0; r < 4; ++r)
                    XAs[(wm * 64 + mt * 16 + l4 * 4 + r) * 8 + l15] = acc_xa[mt][r];
        }
        if (tid < 128) {
            *(float4*)&Bms[tid * 8]     = *(const float4*)&gp.Bm[(size_t)(n0 + tid) * 8];
            *(float4*)&Bms[tid * 8 + 4] = *(const float4*)&gp.Bm[(size_t)(n0 + tid) * 8 + 4];
        }
        __syncthreads();
        const float osc = gp.oscale;
        float bmv[WNT][8], bsv[WNT];
#pragma unroll
        for (int nt = 0; nt < WNT; ++nt) {
            int nloc = wn * 64 + nt * 16 + l15;
            bsv[nt] = gp.bias[n0 + nloc];
#pragma unroll
            for (int q8 = 0; q8 < 8; ++q8) bmv[nt][q8] = Bms[nloc * 8 + q8];
        }
#pragma unroll
        for (int mt = 0; mt < WMT; ++mt)
#pragma unroll
            for (int r = 0; r < 4; ++r) {
                int mloc = wm * 64 + mt * 16 + l4 * 4 + r;
                float xa8[8];
                *(float4*)&xa8[0] = *(const float4*)&XAs[mloc * 8];
                *(float4*)&xa8[4] = *(const float4*)&XAs[mloc * 8 + 4];
#pragma unroll
                for (int nt = 0; nt < WNT; ++nt) {
                    float lora = 0.f;
#pragma unroll
                    for (int q8 = 0; q8 < 8; ++q8) lora += xa8[q8] * bmv[nt][q8];
                    acc[mt][nt][r] = (acc[mt][nt][r] + bsv[nt] + 2.0f * lora) * osc;
                }
            }
        __syncthreads();

        u16* outp = (u16*)gp.out;
        const int bb = m0 >> 11;
        if (gp.transT) {
            // ---- transposed staging: store V plane as [h][d][t] ----
            u16* Lst = smem;   // [128 n][LTT]
#pragma unroll
            for (int ch = 0; ch < 2; ++ch) {
#pragma unroll
                for (int mt2 = 0; mt2 < 2; ++mt2) {
                    int mt = ch * 2 + mt2;
#pragma unroll
                    for (int nt = 0; nt < WNT; ++nt)
#pragma unroll
                        for (int r = 0; r < 4; ++r)
                            Lst[(wn * 64 + nt * 16 + l15) * LTT + wm * 32 + mt2 * 16 + l4 * 4 + r] =
                                f2bf(acc[mt][nt][r]);
                }
                __syncthreads();
#pragma unroll
                for (int j = 0; j < 4; ++j) {
                    int w = tid + j * 256;
                    int nl = w >> 3, seg = w & 7;
                    uint4 val = *(const uint4*)&Lst[nl * LTT + seg * 8];
                    int n = n0 + nl, hh = n >> 6, dd = n & 63;
                    int c0 = seg * 8;
                    int gm = m0 + (c0 >> 5) * 64 + ch * 32 + (c0 & 31);
                    int t = gm & 2047;
                    *(uint4*)&outp[(((size_t)(bb * 16 + hh)) * 64 + dd) * 2048 + t] = val;
                }
                __syncthreads();
            }
        } else {
            // ---- straight staging: [h][t][d] layout ----
            u16* Ls = smem;    // [64][LST]
#pragma unroll
            for (int ch = 0; ch < 2; ++ch) {
#pragma unroll
                for (int mt2 = 0; mt2 < 2; ++mt2) {
                    int mt = ch * 2 + mt2;
#pragma unroll
                    for (int nt = 0; nt < WNT; ++nt)
#pragma unroll
                        for (int r = 0; r < 4; ++r)
                            Ls[(wm * 32 + mt2 * 16 + l4 * 4 + r) * LST + wn * 64 + nt * 16 + l15] =
                                f2bf(acc[mt][nt][r]);
                }
                __syncthreads();
#pragma unroll
                for (int j = 0; j < 4; ++j) {
                    int w = tid + j * 256;
                    int lrow = w >> 4, seg = w & 15;
                    uint4 val = *(const uint4*)&Ls[lrow * LST + seg * 8];
                    int gm = m0 + (lrow >> 5) * 64 + ch * 32 + (lrow & 31);
                    int t = gm & 2047;
                    int n = n0 + seg * 8, hh = n >> 6, dd = n & 63;
                    *(uint4*)&outp[(((size_t)(bb * 16 + hh)) * 2048 + t) * 64 + dd] = val;
                }
                __syncthreads();
            }
        }
    } else {
        float* outp = (float*)gp.out;
#pragma unroll
        for (int mt = 0; mt < WMT; ++mt)
#pragma unroll
            for (int r = 0; r < 4; ++r) {
                int m = m0 + wm * (WMT * 16) + mt * 16 + l4 * 4 + r;
#pragma unroll
                for (int nt = 0; nt < WNT; ++nt) {
                    int n = n0 + wn * (WNT * 16) + nt * 16 + l15;
                    outp[(size_t)m * 1024 + n] = acc[mt][nt][r] + gp.bias[n];
                }
            }
    }
}

// ---------------------------------------------------------------- flash attention
// r2-verified structure (4 waves x 16 q-rows, 256 thr, 16 waves/CU). Swapped-QK^T
// with in-lane P via row-permuted K staging, K/V dbuf via global_load_lds with
// XOR chunk swizzle, 1 barrier/iter. p=exp2(s') -- constant softmax bias cancels
// in normalization (r7-verified).

__global__ __launch_bounds__(256, 4)
void attn_kernel(const u16* __restrict__ QKV, const int* __restrict__ mask,
                 const int* __restrict__ flags, u16* __restrict__ Xo) {
    const int qb = blockIdx.x >> 5;          // 0..31 (64-row q blocks)
    const int bh = blockIdx.x & 31;
    const int b = bh >> 4, h = bh & 15;
    const int tid = threadIdx.x;
    const int lane = tid & 63, wave = tid >> 6;
    const int l15 = lane & 15, l4 = lane >> 4;

    __shared__ alignas(16) u16 Ks[2][64 * 64];    // row-permuted + XOR-swizzled, dbuf
    __shared__ alignas(16) u16 Vts[2][64 * 64];   // [d][k-tile], XOR-swizzled, dbuf

    const size_t plane = (size_t)2 * 16 * 2048 * 64;
    const u16* Qg = QKV + (size_t)(b * 16 + h) * 2048 * 64;   // [t][d] (pre-scaled)
    const u16* Kg = Qg + plane;                                // [t][d]
    const u16* Vg = Kg + plane;                                // [d][t]

    const int srow = lane >> 3;
    const int scol = ((lane & 7) ^ srow) * 8;

    // per-lane staging source pointers (kt-invariant part)
    const u16* kbase[2];
    const u16* vbase[2];
#pragma unroll
    for (int i = 0; i < 2; ++i) {
        int qq = wave * 2 + i;
        // k-col feeding LDS row qq*8+srow (row permutation, see r1 header)
        int kc = 16 * (qq & 1) + 8 * (srow >> 2) + 4 * ((qq >> 1) & 1) + (srow & 3) + 32 * (qq >> 2);
        kbase[i] = Kg + (size_t)kc * 64 + scol;
        vbase[i] = Vg + (size_t)(qq * 8 + srow) * 2048 + scol;
    }

    // Q fragments in registers (wave owns 16 q-rows)
    bf16x8 qa[2];
#pragma unroll
    for (int kk2 = 0; kk2 < 2; ++kk2)
        qa[kk2] = *(const bf16x8*)&Qg[(size_t)(qb * 64 + wave * 16 + l15) * 64 + kk2 * 32 + l4 * 8];

    const f32x4 fz = {0.f, 0.f, 0.f, 0.f};
    f32x4 accO[4];
#pragma unroll
    for (int dt = 0; dt < 4; ++dt) accO[dt] = fz;
    float lsum = 0.f;

    // prologue: stage tile 0 into buffer 0
#pragma unroll
    for (int i = 0; i < 2; ++i) {
        int qq = wave * 2 + i;
        gl2lds16(kbase[i], &Ks[0][qq * 512]);
        gl2lds16(vbase[i], &Vts[0][qq * 512]);
    }
    __syncthreads();   // vmcnt drain: tile 0 landed

    for (int kt = 0; kt < 32; ++kt) {
        const u16* Kc = &Ks[kt & 1][0];
        const u16* Vc = &Vts[kt & 1][0];

        // issue next tile's DMA into the other buffer; latency hides under compute
        if (kt < 31) {
            u16* Kn = &Ks[(kt + 1) & 1][0];
            u16* Vn = &Vts[(kt + 1) & 1][0];
#pragma unroll
            for (int i = 0; i < 2; ++i) {
                int qq = wave * 2 + i;
                gl2lds16(kbase[i] + (size_t)(kt + 1) * 4096, &Kn[qq * 512]);
                gl2lds16(vbase[i] + (size_t)(kt + 1) * 64, &Vn[qq * 512]);
            }
        }

        // S^T = K Q^T: accS[j] col = q-row l15, row m -> k-col 8*l4+4*(j&1)+r+32*(j>>1)
        f32x4 accS[4];
#pragma unroll
        for (int j = 0; j < 4; ++j) accS[j] = fz;
#pragma unroll
        for (int kk2 = 0; kk2 < 2; ++kk2) {
            bf16x8 kf[4];
#pragma unroll
            for (int j = 0; j < 4; ++j)
                kf[j] = *(const bf16x8*)&Kc[(j * 16 + l15) * 64 + (((kk2 * 4 + l4) ^ (l15 & 7)) * 8)];
            __builtin_amdgcn_s_setprio(1);
#pragma unroll
            for (int j = 0; j < 4; ++j)
                accS[j] = __builtin_amdgcn_mfma_f32_16x16x32_bf16(kf[j], qa[kk2], accS[j], 0, 0, 0);
            __builtin_amdgcn_s_setprio(0);
        }

        if (flags[(qb >> 1) * 32 + kt] == 0) {
            int qrow = qb * 64 + wave * 16 + l15;
#pragma unroll
            for (int j = 0; j < 4; ++j)
#pragma unroll
                for (int r = 0; r < 4; ++r) {
                    int kcol = kt * 64 + 8 * l4 + 4 * (j & 1) + r + 32 * (j >> 1);
                    if (mask[(size_t)qrow * 2048 + kcol] == 0) accS[j][r] = -1e9f;
                }
        }

        // p = exp2(s'); constant softmax bias dropped (cancels in normalization)
        float part0 = 0.f, part1 = 0.f;
#pragma unroll
        for (int j = 0; j < 4; ++j)
#pragma unroll
            for (int r = 0; r < 4; ++r) {
                float p = EXP2(accS[j][r]);
                accS[j][r] = p;
                if (j & 1) part1 += p; else part0 += p;
            }
        lsum += part0 + part1;

        // PV A-fragment built fully in-lane: j0,j1 -> kk2=0 cols 8*l4+0..7; j2,j3 -> kk2=1
        u32x4 paw0, paw1;
        paw0[0] = cvtpk(accS[0][0], accS[0][1]); paw0[1] = cvtpk(accS[0][2], accS[0][3]);
        paw0[2] = cvtpk(accS[1][0], accS[1][1]); paw0[3] = cvtpk(accS[1][2], accS[1][3]);
        paw1[0] = cvtpk(accS[2][0], accS[2][1]); paw1[1] = cvtpk(accS[2][2], accS[2][3]);
        paw1[2] = cvtpk(accS[3][0], accS[3][1]); paw1[3] = cvtpk(accS[3][2], accS[3][3]);
        bf16x8 pa[2];
        pa[0] = __builtin_bit_cast(bf16x8, paw0);
        pa[1] = __builtin_bit_cast(bf16x8, paw1);

        // O += P V
#pragma unroll
        for (int kk2 = 0; kk2 < 2; ++kk2) {
            bf16x8 vf[4];
#pragma unroll
            for (int dt = 0; dt < 4; ++dt)
                vf[dt] = *(const bf16x8*)&Vc[(dt * 16 + l15) * 64 + (((kk2 * 4 + l4) ^ (l15 & 7)) * 8)];
            __builtin_amdgcn_s_setprio(1);
#pragma unroll
            for (int dt = 0; dt < 4; ++dt)
                accO[dt] = __builtin_amdgcn_mfma_f32_16x16x32_bf16(pa[kk2], vf[dt], accO[dt], 0, 0, 0);
            __builtin_amdgcn_s_setprio(0);
        }

        // single barrier per iteration: drains next tile's DMA (vmcnt(0)) and
        // guarantees all waves finished reading buf cur before it is overwritten
        __syncthreads();
    }

    // row totals: lane holds partial for q-row l15; reduce over the 4 l4 copies
    float tot = lsum;
    tot += __shfl_xor(tot, 16, 64);
    tot += __shfl_xor(tot, 32, 64);
    float inv[4];
#pragma unroll
    for (int r = 0; r < 4; ++r) inv[r] = 1.0f / __shfl(tot, l4 * 4 + r, 64);

    // LDS-staged coalesced output (reuse Ks[0]; XOR chunk swizzle)
    u16* Es = &Ks[0][0];
#pragma unroll
    for (int dt = 0; dt < 4; ++dt)
#pragma unroll
        for (int r = 0; r < 4; ++r) {
            int prow = wave * 16 + l4 * 4 + r;
            Es[prow * 64 + (((dt * 2 + (l15 >> 3)) ^ (prow & 7)) * 8) + (l15 & 7)] =
                f2bf(accO[dt][r] * inv[r]);
        }
    __syncthreads();
#pragma unroll
    for (int j = 0; j < 2; ++j) {
        int w = tid + j * 256;            // 512: 64 rows x 8 segs
        int row = w >> 3, seg = w & 7;
        uint4 val = *(const uint4*)&Es[row * 64 + ((seg ^ (row & 7)) * 8)];
        int t = qb * 64 + row;
        *(uint4*)&Xo[((size_t)(b * 2048 + t)) * 1024 + h * 64 + seg * 8] = val;
    }
}

// ---------------------------------------------------------------- launch
extern "C" void kernel_launch(void* const* d_in, const int* in_sizes, int n_in,
                              void* d_out, int out_size, void* d_ws, size_t ws_size,
                              hipStream_t stream) {
    const float* q    = (const float*)d_in[0];
    const float* k    = (const float*)d_in[1];
    const float* v    = (const float*)d_in[2];
    const int*   mask = (const int*)d_in[3];
    const float* Wq = (const float*)d_in[4];
    const float* bq = (const float*)d_in[5];
    const float* Aq = (const float*)d_in[6];
    const float* Bq = (const float*)d_in[7];
    const float* Wk = (const float*)d_in[8];
    const float* bk = (const float*)d_in[9];
    const float* Ak = (const float*)d_in[10];
    const float* Bk = (const float*)d_in[11];
    const float* Wv = (const float*)d_in[12];
    const float* bv = (const float*)d_in[13];
    const float* Av = (const float*)d_in[14];
    const float* Bv = (const float*)d_in[15];
    const float* Wo = (const float*)d_in[16];
    const float* bo = (const float*)d_in[17];

    char* ws = (char*)d_ws;
    u16*   QKV   = (u16*)ws;                    // Q,K: [b][h][t][d]; V: [b][h][d][t]
    u16*   qb16  = (u16*)(ws + 25165824);
    u16*   kb16  = (u16*)(ws + 33554432);
    u16*   vb16  = (u16*)(ws + 41943040);
    u16*   Wqb   = (u16*)(ws + 50331648);
    u16*   Wkb   = (u16*)(ws + 52428800);
    u16*   Wvb   = (u16*)(ws + 54525952);
    u16*   Wob   = (u16*)(ws + 56623104);
    u16*   Apk   = (u16*)(ws + 58720256);       // 3 x 16384 u16 packed A frags
    int*   flags = (int*)(ws + 59113472);
    u16*   Xbuf  = qb16;

    PrepArgs pa;
    pa.csrc[0] = q;  pa.csrc[1] = k;  pa.csrc[2] = v;
    pa.csrc[3] = Wq; pa.csrc[4] = Wk; pa.csrc[5] = Wv; pa.csrc[6] = Wo;
    pa.cdst[0] = qb16; pa.cdst[1] = kb16; pa.cdst[2] = vb16;
    pa.cdst[3] = Wqb;  pa.cdst[4] = Wkb;  pa.cdst[5] = Wvb; pa.cdst[6] = Wob;
    pa.A[0] = Aq; pa.A[1] = Ak; pa.A[2] = Av;
    pa.apk[0] = Apk; pa.apk[1] = Apk + 16384; pa.apk[2] = Apk + 32768;
    pa.mask = mask; pa.flags = flags;
    prep_kernel<<<dim3(1539), dim3(256), 0, stream>>>(pa);

    const float QSCALE = 0.1803368801f;   // 0.125 * log2(e)
    GemmArgs g1;
    g1.p[0] = GemmPtrs{qb16, Wqb, bq, Apk,         Bq, (void*)QKV,             0, QSCALE};
    g1.p[1] = GemmPtrs{kb16, Wkb, bk, Apk + 16384, Bk, (void*)(QKV + 4194304), 0, 1.0f};
    g1.p[2] = GemmPtrs{vb16, Wvb, bv, Apk + 32768, Bv, (void*)(QKV + 8388608), 1, 1.0f};
    gemm_kernel<4, 4, 1><<<dim3(256, 1, 3), dim3(256), 0, stream>>>(g1);

    attn_kernel<<<dim3(1024), dim3(256), 0, stream>>>(QKV, mask, flags, Xbuf);

    GemmArgs g2;
    g2.p[0] = GemmPtrs{Xbuf, Wob, bo, nullptr, nullptr, d_out, 0, 1.0f};
    g2.p[1] = g2.p[0];
    g2.p[2] = g2.p[0];
    gemm_kernel<2, 4, 0><<<dim3(512, 1, 1), dim3(256), 0, stream>>>(g2);
}

// Round 11
// 245.049 us; speedup vs baseline: 1.1233x; 1.0423x over previous
//
#include <hip/hip_runtime.h>
#include <stdint.h>

typedef unsigned short u16;
typedef __attribute__((ext_vector_type(4))) float f32x4;
typedef __attribute__((ext_vector_type(4))) uint32_t u32x4;
typedef __attribute__((ext_vector_type(8))) __bf16 bf16x8;

#if __has_builtin(__builtin_amdgcn_exp2f)
#define EXP2(x) __builtin_amdgcn_exp2f(x)
#else
#define EXP2(x) exp2f(x)
#endif

static __device__ __forceinline__ u16 f2bf(float f) {
    union { float f; uint32_t i; } v; v.f = f;
    return (u16)((v.i + 0x7FFFu + ((v.i >> 16) & 1u)) >> 16);
}
// packed f32x2 -> bf16x2 (RNE), single VALU op
static __device__ __forceinline__ uint32_t cvtpk(float lo, float hi) {
    uint32_t r;
    asm("v_cvt_pk_bf16_f32 %0, %1, %2" : "=v"(r) : "v"(lo), "v"(hi));
    return r;
}

// async global->LDS DMA, 16 B per lane; lds dest = wave-uniform base + lane*16
static __device__ __forceinline__ void gl2lds16(const u16* g, u16* lds) {
    __builtin_amdgcn_global_load_lds(
        (const __attribute__((address_space(1))) void*)g,
        (__attribute__((address_space(3))) void*)lds, 16, 0, 0);
}

// ---------------------------------------------------------------- fused prologue
// blocks [0,1024): f32->bf16 casts  (x: 3x256 blocks, W: 4x64 blocks)
// blocks [1024,1536): mask all-ones tile flags
// blocks [1536,1539): A zero-padded bf16 fragment-pack (one block per z)
struct PrepArgs {
    const float* csrc[7]; u16* cdst[7];   // q,k,v,Wq,Wk,Wv,Wo
    const float* A[3]; u16* apk[3];       // A pack: [kb*2+kk2][lane][8] bf16
    const int* mask; int* flags;
};

__global__ __launch_bounds__(256)
void prep_kernel(PrepArgs a) {
    const int bid = blockIdx.x;
    const int tid = threadIdx.x;

    if (bid < 1024) {
        // ---- streaming f32 -> bf16 cast (16384 elems per block) ----
        int arr, boff;
        if (bid < 768) { arr = bid >> 8; boff = bid & 255; }
        else { int b2 = bid - 768; arr = 3 + (b2 >> 6); boff = b2 & 63; }
        const float* s = a.csrc[arr] + (size_t)boff * 16384;
        u16* d = a.cdst[arr] + (size_t)boff * 16384;
#pragma unroll
        for (int i = 0; i < 8; ++i) {
            int c = tid + i * 256;
            float4 f0 = *(const float4*)(s + c * 8);
            float4 f1 = *(const float4*)(s + c * 8 + 4);
            u16 o[8];
            o[0] = f2bf(f0.x); o[1] = f2bf(f0.y); o[2] = f2bf(f0.z); o[3] = f2bf(f0.w);
            o[4] = f2bf(f1.x); o[5] = f2bf(f1.y); o[6] = f2bf(f1.z); o[7] = f2bf(f1.w);
            *(uint4*)(d + c * 8) = *(const uint4*)o;
        }
    } else if (bid < 1536) {
        // ---- mask flags ----
        const int b3 = bid - 1024;
        const int qb = b3 & 15, kt = b3 >> 4;
        int ok = 1;
#pragma unroll
        for (int i = 0; i < 8; ++i) {
            int c = tid + i * 256;
            int row = c >> 4, cg = c & 15;
            int4 m4 = *(const int4*)&a.mask[(size_t)(qb * 128 + row) * 2048 + kt * 64 + cg * 4];
            ok &= (m4.x != 0) & (m4.y != 0) & (m4.z != 0) & (m4.w != 0);
        }
        int wall = __all(ok) ? 1 : 0;
        __shared__ int red[4];
        if ((tid & 63) == 0) red[tid >> 6] = wall;
        __syncthreads();
        if (tid == 0) a.flags[qb * 32 + kt] = red[0] & red[1] & red[2] & red[3];
    } else {
        // ---- A fragment-pack: apk[((kb*2+kk2)*64 + lane)*8 + j] =
        //      (l15<8) ? bf16(A[l15][kb*64 + kk2*32 + l4*8 + j]) : 0 ----
        const int z = bid - 1536;
        const float* Az = a.A[z];
        u16* dp = a.apk[z];
#pragma unroll
        for (int i = 0; i < 8; ++i) {
            int pos = tid + i * 256;           // 2048 fragment chunks
            int lane2 = pos & 63;
            int l15_ = lane2 & 15, l4_ = lane2 >> 4;
            int kbkk = pos >> 6;
            int kcol = (kbkk >> 1) * 64 + (kbkk & 1) * 32 + l4_ * 8;
            u16 ob[8] = {0, 0, 0, 0, 0, 0, 0, 0};
            if (l15_ < 8) {
                float4 f0 = *(const float4*)&Az[(size_t)l15_ * 1024 + kcol];
                float4 f1 = *(const float4*)&Az[(size_t)l15_ * 1024 + kcol + 4];
                ob[0] = f2bf(f0.x); ob[1] = f2bf(f0.y); ob[2] = f2bf(f0.z); ob[3] = f2bf(f0.w);
                ob[4] = f2bf(f1.x); ob[5] = f2bf(f1.y); ob[6] = f2bf(f1.z); ob[7] = f2bf(f1.w);
            }
            *(uint4*)&dp[(size_t)pos * 8] = *(const uint4*)ob;
        }
    }
}

// ---------------------------------------------------------------- GEMM  C = (X·W^T + bias + 2·XA·Bm^T) * oscale
// r11: K-loop DOUBLE-BUFFERED (attn-r0-verified pattern): tile kb+1's DMA is
// issued at the top of iteration kb into buf[(kb+1)&1]; compute reads buf[kb&1];
// ONE barrier per iteration (its implicit vmcnt(0) drain lands after ~600cy of
// compute instead of immediately). abf (packed A) fragments prefetched one kb
// ahead BEFORE the gl2lds batch, so their FIFO vmcnt wait doesn't drain staging.
// Was: 2 barriers/iter, 55.5us, MfmaUtil 21%, no pipe >22% (latency-exposed).
struct GemmPtrs { const u16* X; const u16* W; const float* bias; const u16* Ap; const float* Bm; void* out; int transT; float oscale; };
struct GemmArgs { GemmPtrs p[3]; };

#define LST 136  // straight epilogue staging row stride (u16)
#define LTT 72   // transposed epilogue staging row stride (u16)

template <int WMT, int WNT, int LORA>
__global__ __launch_bounds__(256, 2)
void gemm_kernel(GemmArgs args) {
    constexpr int BM = WMT * 32, BN = WNT * 32;
    constexpr int MBLK = 4096 / BM;
    constexpr int IPA = BM / 32;
    constexpr int IPB = BN / 32;
    __shared__ alignas(16) u16 smem[2][(BM + BN) * 64];   // double-buffered K-tiles

    const GemmPtrs gp = args.p[blockIdx.z];
    const int tid = threadIdx.x;
    const int lane = tid & 63, wave = tid >> 6;
    const int wm = wave >> 1, wn = wave & 1;
    const int l15 = lane & 15, l4 = lane >> 4;
    const int id = blockIdx.x;
    const int m0 = (id % MBLK) * BM, n0 = (id / MBLK) * BN;

    const int srow = lane >> 3;
    const int scol = ((lane & 7) ^ srow) * 8;
    const u16* gA[IPA];
    const u16* gB[IPB];
#pragma unroll
    for (int i = 0; i < IPA; ++i) {
        int q = wave * IPA + i;
        gA[i] = gp.X + (size_t)(m0 + q * 8 + srow) * 1024 + scol;
    }
#pragma unroll
    for (int i = 0; i < IPB; ++i) {
        int q = wave * IPB + i;
        gB[i] = gp.W + (size_t)(n0 + q * 8 + srow) * 1024 + scol;
    }

    const f32x4 fz = {0.f, 0.f, 0.f, 0.f};
    f32x4 acc[WMT][WNT];
#pragma unroll
    for (int i = 0; i < WMT; ++i)
#pragma unroll
        for (int j = 0; j < WNT; ++j) acc[i][j] = fz;
    f32x4 acc_xa[WMT];
    bf16x8 abf[2], abf_n[2];
    if constexpr (LORA) {
#pragma unroll
        for (int i = 0; i < WMT; ++i) acc_xa[i] = fz;
        abf[0] = *(const bf16x8*)&gp.Ap[(size_t)(0 * 64 + lane) * 8];
        abf[1] = *(const bf16x8*)&gp.Ap[(size_t)(1 * 64 + lane) * 8];
    }

    // prologue: stage K-tile 0 into buffer 0
#pragma unroll
    for (int i = 0; i < IPA; ++i)
        gl2lds16(gA[i], &smem[0][(wave * IPA + i) * 512]);
#pragma unroll
    for (int i = 0; i < IPB; ++i)
        gl2lds16(gB[i], &smem[0][BM * 64 + (wave * IPB + i) * 512]);
    __syncthreads();   // vmcnt drain: tile 0 landed

    const int sw = l15 & 7;
    for (int kb = 0; kb < 16; ++kb) {
        const u16* As = &smem[kb & 1][0];
        const u16* Bs = &smem[kb & 1][BM * 64];

        if (kb < 15) {
            // abf prefetch FIRST (FIFO: its wait then needs vmcnt(8), no staging drain)
            if constexpr (LORA) {
                abf_n[0] = *(const bf16x8*)&gp.Ap[(size_t)(((kb + 1) * 2 + 0) * 64 + lane) * 8];
                abf_n[1] = *(const bf16x8*)&gp.Ap[(size_t)(((kb + 1) * 2 + 1) * 64 + lane) * 8];
            }
            u16* An = &smem[(kb + 1) & 1][0];
            u16* Bn = &smem[(kb + 1) & 1][BM * 64];
#pragma unroll
            for (int i = 0; i < IPA; ++i)
                gl2lds16(gA[i] + (kb + 1) * 64, &An[(wave * IPA + i) * 512]);
#pragma unroll
            for (int i = 0; i < IPB; ++i)
                gl2lds16(gB[i] + (kb + 1) * 64, &Bn[(wave * IPB + i) * 512]);
        }

#pragma unroll
        for (int kk2 = 0; kk2 < 2; ++kk2) {
            bf16x8 af[WMT], bfr[WNT];
#pragma unroll
            for (int mt = 0; mt < WMT; ++mt) {
                int x = wm * (WMT * 16) + mt * 16 + l15;
                af[mt] = *(const bf16x8*)&As[x * 64 + (((kk2 * 4 + l4) ^ sw) * 8)];
            }
#pragma unroll
            for (int nt = 0; nt < WNT; ++nt) {
                int y = wn * (WNT * 16) + nt * 16 + l15;
                bfr[nt] = *(const bf16x8*)&Bs[y * 64 + (((kk2 * 4 + l4) ^ sw) * 8)];
            }
#pragma unroll
            for (int mt = 0; mt < WMT; ++mt)
#pragma unroll
                for (int nt = 0; nt < WNT; ++nt)
                    acc[mt][nt] = __builtin_amdgcn_mfma_f32_16x16x32_bf16(af[mt], bfr[nt], acc[mt][nt], 0, 0, 0);
            if constexpr (LORA) {
#pragma unroll
                for (int mt = 0; mt < WMT; ++mt)
                    acc_xa[mt] = __builtin_amdgcn_mfma_f32_16x16x32_bf16(af[mt], abf[kk2], acc_xa[mt], 0, 0, 0);
            }
        }
        if constexpr (LORA) {
            if (kb < 15) { abf[0] = abf_n[0]; abf[1] = abf_n[1]; }
        }

        // single barrier per K-step: drains next tile's DMA and gates buffer reuse
        __syncthreads();
    }

    if constexpr (LORA) {
        // ---- fold (bias + 2*XA·Bm^T) and oscale into acc (BM==BN==128) ----
        float* XAs = (float*)&smem[0][0];
        float* Bms = (float*)&smem[0][BM * 64];
        // store in-kernel XA fragments: C-layout row=wm*64+mt*16+l4*4+r, col=l15
        if (wn == 0 && l15 < 8) {
#pragma unroll
            for (int mt = 0; mt < WMT; ++mt)
#pragma unroll
                for (int r = 0; r < 4; ++r)
                    XAs[(wm * 64 + mt * 16 + l4 * 4 + r) * 8 + l15] = acc_xa[mt][r];
        }
        if (tid < 128) {
            *(float4*)&Bms[tid * 8]     = *(const float4*)&gp.Bm[(size_t)(n0 + tid) * 8];
            *(float4*)&Bms[tid * 8 + 4] = *(const float4*)&gp.Bm[(size_t)(n0 + tid) * 8 + 4];
        }
        __syncthreads();
        const float osc = gp.oscale;
        float bmv[WNT][8], bsv[WNT];
#pragma unroll
        for (int nt = 0; nt < WNT; ++nt) {
            int nloc = wn * 64 + nt * 16 + l15;
            bsv[nt] = gp.bias[n0 + nloc];
#pragma unroll
            for (int q8 = 0; q8 < 8; ++q8) bmv[nt][q8] = Bms[nloc * 8 + q8];
        }
#pragma unroll
        for (int mt = 0; mt < WMT; ++mt)
#pragma unroll
            for (int r = 0; r < 4; ++r) {
                int mloc = wm * 64 + mt * 16 + l4 * 4 + r;
                float xa8[8];
                *(float4*)&xa8[0] = *(const float4*)&XAs[mloc * 8];
                *(float4*)&xa8[4] = *(const float4*)&XAs[mloc * 8 + 4];
#pragma unroll
                for (int nt = 0; nt < WNT; ++nt) {
                    float lora = 0.f;
#pragma unroll
                    for (int q8 = 0; q8 < 8; ++q8) lora += xa8[q8] * bmv[nt][q8];
                    acc[mt][nt][r] = (acc[mt][nt][r] + bsv[nt] + 2.0f * lora) * osc;
                }
            }
        __syncthreads();

        u16* outp = (u16*)gp.out;
        const int bb = m0 >> 11;
        if (gp.transT) {
            // ---- transposed staging: store V plane as [h][d][t] ----
            u16* Lst = &smem[0][0];   // [128 n][LTT]
#pragma unroll
            for (int ch = 0; ch < 2; ++ch) {
#pragma unroll
                for (int mt2 = 0; mt2 < 2; ++mt2) {
                    int mt = ch * 2 + mt2;
#pragma unroll
                    for (int nt = 0; nt < WNT; ++nt)
#pragma unroll
                        for (int r = 0; r < 4; ++r)
                            Lst[(wn * 64 + nt * 16 + l15) * LTT + wm * 32 + mt2 * 16 + l4 * 4 + r] =
                                f2bf(acc[mt][nt][r]);
                }
                __syncthreads();
#pragma unroll
                for (int j = 0; j < 4; ++j) {
                    int w = tid + j * 256;
                    int nl = w >> 3, seg = w & 7;
                    uint4 val = *(const uint4*)&Lst[nl * LTT + seg * 8];
                    int n = n0 + nl, hh = n >> 6, dd = n & 63;
                    int c0 = seg * 8;
                    int gm = m0 + (c0 >> 5) * 64 + ch * 32 + (c0 & 31);
                    int t = gm & 2047;
                    *(uint4*)&outp[(((size_t)(bb * 16 + hh)) * 64 + dd) * 2048 + t] = val;
                }
                __syncthreads();
            }
        } else {
            // ---- straight staging: [h][t][d] layout ----
            u16* Ls = &smem[0][0];    // [64][LST]
#pragma unroll
            for (int ch = 0; ch < 2; ++ch) {
#pragma unroll
                for (int mt2 = 0; mt2 < 2; ++mt2) {
                    int mt = ch * 2 + mt2;
#pragma unroll
                    for (int nt = 0; nt < WNT; ++nt)
#pragma unroll
                        for (int r = 0; r < 4; ++r)
                            Ls[(wm * 32 + mt2 * 16 + l4 * 4 + r) * LST + wn * 64 + nt * 16 + l15] =
                                f2bf(acc[mt][nt][r]);
                }
                __syncthreads();
#pragma unroll
                for (int j = 0; j < 4; ++j) {
                    int w = tid + j * 256;
                    int lrow = w >> 4, seg = w & 15;
                    uint4 val = *(const uint4*)&Ls[lrow * LST + seg * 8];
                    int gm = m0 + (lrow >> 5) * 64 + ch * 32 + (lrow & 31);
                    int t = gm & 2047;
                    int n = n0 + seg * 8, hh = n >> 6, dd = n & 63;
                    *(uint4*)&outp[(((size_t)(bb * 16 + hh)) * 2048 + t) * 64 + dd] = val;
                }
                __syncthreads();
            }
        }
    } else {
        float* outp = (float*)gp.out;
#pragma unroll
        for (int mt = 0; mt < WMT; ++mt)
#pragma unroll
            for (int r = 0; r < 4; ++r) {
                int m = m0 + wm * (WMT * 16) + mt * 16 + l4 * 4 + r;
#pragma unroll
                for (int nt = 0; nt < WNT; ++nt) {
                    int n = n0 + wn * (WNT * 16) + nt * 16 + l15;
                    outp[(size_t)m * 1024 + n] = acc[mt][nt][r] + gp.bias[n];
                }
            }
    }
}

// ---------------------------------------------------------------- flash attention
// r2-verified structure (4 waves x 16 q-rows, 256 thr, 16 waves/CU). Swapped-QK^T
// with in-lane P via row-permuted K staging, K/V dbuf via global_load_lds with
// XOR chunk swizzle, 1 barrier/iter. p=exp2(s') -- constant softmax bias cancels
// in normalization (r7-verified).

__global__ __launch_bounds__(256, 4)
void attn_kernel(const u16* __restrict__ QKV, const int* __restrict__ mask,
                 const int* __restrict__ flags, u16* __restrict__ Xo) {
    const int qb = blockIdx.x >> 5;          // 0..31 (64-row q blocks)
    const int bh = blockIdx.x & 31;
    const int b = bh >> 4, h = bh & 15;
    const int tid = threadIdx.x;
    const int lane = tid & 63, wave = tid >> 6;
    const int l15 = lane & 15, l4 = lane >> 4;

    __shared__ alignas(16) u16 Ks[2][64 * 64];    // row-permuted + XOR-swizzled, dbuf
    __shared__ alignas(16) u16 Vts[2][64 * 64];   // [d][k-tile], XOR-swizzled, dbuf

    const size_t plane = (size_t)2 * 16 * 2048 * 64;
    const u16* Qg = QKV + (size_t)(b * 16 + h) * 2048 * 64;   // [t][d] (pre-scaled)
    const u16* Kg = Qg + plane;                                // [t][d]
    const u16* Vg = Kg + plane;                                // [d][t]

    const int srow = lane >> 3;
    const int scol = ((lane & 7) ^ srow) * 8;

    // per-lane staging source pointers (kt-invariant part)
    const u16* kbase[2];
    const u16* vbase[2];
#pragma unroll
    for (int i = 0; i < 2; ++i) {
        int qq = wave * 2 + i;
        // k-col feeding LDS row qq*8+srow (row permutation, see r1 header)
        int kc = 16 * (qq & 1) + 8 * (srow >> 2) + 4 * ((qq >> 1) & 1) + (srow & 3) + 32 * (qq >> 2);
        kbase[i] = Kg + (size_t)kc * 64 + scol;
        vbase[i] = Vg + (size_t)(qq * 8 + srow) * 2048 + scol;
    }

    // Q fragments in registers (wave owns 16 q-rows)
    bf16x8 qa[2];
#pragma unroll
    for (int kk2 = 0; kk2 < 2; ++kk2)
        qa[kk2] = *(const bf16x8*)&Qg[(size_t)(qb * 64 + wave * 16 + l15) * 64 + kk2 * 32 + l4 * 8];

    const f32x4 fz = {0.f, 0.f, 0.f, 0.f};
    f32x4 accO[4];
#pragma unroll
    for (int dt = 0; dt < 4; ++dt) accO[dt] = fz;
    float lsum = 0.f;

    // prologue: stage tile 0 into buffer 0
#pragma unroll
    for (int i = 0; i < 2; ++i) {
        int qq = wave * 2 + i;
        gl2lds16(kbase[i], &Ks[0][qq * 512]);
        gl2lds16(vbase[i], &Vts[0][qq * 512]);
    }
    __syncthreads();   // vmcnt drain: tile 0 landed

    for (int kt = 0; kt < 32; ++kt) {
        const u16* Kc = &Ks[kt & 1][0];
        const u16* Vc = &Vts[kt & 1][0];

        // issue next tile's DMA into the other buffer; latency hides under compute
        if (kt < 31) {
            u16* Kn = &Ks[(kt + 1) & 1][0];
            u16* Vn = &Vts[(kt + 1) & 1][0];
#pragma unroll
            for (int i = 0; i < 2; ++i) {
                int qq = wave * 2 + i;
                gl2lds16(kbase[i] + (size_t)(kt + 1) * 4096, &Kn[qq * 512]);
                gl2lds16(vbase[i] + (size_t)(kt + 1) * 64, &Vn[qq * 512]);
            }
        }

        // S^T = K Q^T: accS[j] col = q-row l15, row m -> k-col 8*l4+4*(j&1)+r+32*(j>>1)
        f32x4 accS[4];
#pragma unroll
        for (int j = 0; j < 4; ++j) accS[j] = fz;
#pragma unroll
        for (int kk2 = 0; kk2 < 2; ++kk2) {
            bf16x8 kf[4];
#pragma unroll
            for (int j = 0; j < 4; ++j)
                kf[j] = *(const bf16x8*)&Kc[(j * 16 + l15) * 64 + (((kk2 * 4 + l4) ^ (l15 & 7)) * 8)];
            __builtin_amdgcn_s_setprio(1);
#pragma unroll
            for (int j = 0; j < 4; ++j)
                accS[j] = __builtin_amdgcn_mfma_f32_16x16x32_bf16(kf[j], qa[kk2], accS[j], 0, 0, 0);
            __builtin_amdgcn_s_setprio(0);
        }

        if (flags[(qb >> 1) * 32 + kt] == 0) {
            int qrow = qb * 64 + wave * 16 + l15;
#pragma unroll
            for (int j = 0; j < 4; ++j)
#pragma unroll
                for (int r = 0; r < 4; ++r) {
                    int kcol = kt * 64 + 8 * l4 + 4 * (j & 1) + r + 32 * (j >> 1);
                    if (mask[(size_t)qrow * 2048 + kcol] == 0) accS[j][r] = -1e9f;
                }
        }

        // p = exp2(s'); constant softmax bias dropped (cancels in normalization)
        float part0 = 0.f, part1 = 0.f;
#pragma unroll
        for (int j = 0; j < 4; ++j)
#pragma unroll
            for (int r = 0; r < 4; ++r) {
                float p = EXP2(accS[j][r]);
                accS[j][r] = p;
                if (j & 1) part1 += p; else part0 += p;
            }
        lsum += part0 + part1;

        // PV A-fragment built fully in-lane: j0,j1 -> kk2=0 cols 8*l4+0..7; j2,j3 -> kk2=1
        u32x4 paw0, paw1;
        paw0[0] = cvtpk(accS[0][0], accS[0][1]); paw0[1] = cvtpk(accS[0][2], accS[0][3]);
        paw0[2] = cvtpk(accS[1][0], accS[1][1]); paw0[3] = cvtpk(accS[1][2], accS[1][3]);
        paw1[0] = cvtpk(accS[2][0], accS[2][1]); paw1[1] = cvtpk(accS[2][2], accS[2][3]);
        paw1[2] = cvtpk(accS[3][0], accS[3][1]); paw1[3] = cvtpk(accS[3][2], accS[3][3]);
        bf16x8 pa[2];
        pa[0] = __builtin_bit_cast(bf16x8, paw0);
        pa[1] = __builtin_bit_cast(bf16x8, paw1);

        // O += P V
#pragma unroll
        for (int kk2 = 0; kk2 < 2; ++kk2) {
            bf16x8 vf[4];
#pragma unroll
            for (int dt = 0; dt < 4; ++dt)
                vf[dt] = *(const bf16x8*)&Vc[(dt * 16 + l15) * 64 + (((kk2 * 4 + l4) ^ (l15 & 7)) * 8)];
            __builtin_amdgcn_s_setprio(1);
#pragma unroll
            for (int dt = 0; dt < 4; ++dt)
                accO[dt] = __builtin_amdgcn_mfma_f32_16x16x32_bf16(pa[kk2], vf[dt], accO[dt], 0, 0, 0);
            __builtin_amdgcn_s_setprio(0);
        }

        // single barrier per iteration: drains next tile's DMA (vmcnt(0)) and
        // guarantees all waves finished reading buf cur before it is overwritten
        __syncthreads();
    }

    // row totals: lane holds partial for q-row l15; reduce over the 4 l4 copies
    float tot = lsum;
    tot += __shfl_xor(tot, 16, 64);
    tot += __shfl_xor(tot, 32, 64);
    float inv[4];
#pragma unroll
    for (int r = 0; r < 4; ++r) inv[r] = 1.0f / __shfl(tot, l4 * 4 + r, 64);

    // LDS-staged coalesced output (reuse Ks[0]; XOR chunk swizzle)
    u16* Es = &Ks[0][0];
#pragma unroll
    for (int dt = 0; dt < 4; ++dt)
#pragma unroll
        for (int r = 0; r < 4; ++r) {
            int prow = wave * 16 + l4 * 4 + r;
            Es[prow * 64 + (((dt * 2 + (l15 >> 3)) ^ (prow & 7)) * 8) + (l15 & 7)] =
                f2bf(accO[dt][r] * inv[r]);
        }
    __syncthreads();
#pragma unroll
    for (int j = 0; j < 2; ++j) {
        int w = tid + j * 256;            // 512: 64 rows x 8 segs
        int row = w >> 3, seg = w & 7;
        uint4 val = *(const uint4*)&Es[row * 64 + ((seg ^ (row & 7)) * 8)];
        int t = qb * 64 + row;
        *(uint4*)&Xo[((size_t)(b * 2048 + t)) * 1024 + h * 64 + seg * 8] = val;
    }
}

// ---------------------------------------------------------------- launch
extern "C" void kernel_launch(void* const* d_in, const int* in_sizes, int n_in,
                              void* d_out, int out_size, void* d_ws, size_t ws_size,
                              hipStream_t stream) {
    const float* q    = (const float*)d_in[0];
    const float* k    = (const float*)d_in[1];
    const float* v    = (const float*)d_in[2];
    const int*   mask = (const int*)d_in[3];
    const float* Wq = (const float*)d_in[4];
    const float* bq = (const float*)d_in[5];
    const float* Aq = (const float*)d_in[6];
    const float* Bq = (const float*)d_in[7];
    const float* Wk = (const float*)d_in[8];
    const float* bk = (const float*)d_in[9];
    const float* Ak = (const float*)d_in[10];
    const float* Bk = (const float*)d_in[11];
    const float* Wv = (const float*)d_in[12];
    const float* bv = (const float*)d_in[13];
    const float* Av = (const float*)d_in[14];
    const float* Bv = (const float*)d_in[15];
    const float* Wo = (const float*)d_in[16];
    const float* bo = (const float*)d_in[17];

    char* ws = (char*)d_ws;
    u16*   QKV   = (u16*)ws;                    // Q,K: [b][h][t][d]; V: [b][h][d][t]
    u16*   qb16  = (u16*)(ws + 25165824);
    u16*   kb16  = (u16*)(ws + 33554432);
    u16*   vb16  = (u16*)(ws + 41943040);
    u16*   Wqb   = (u16*)(ws + 50331648);
    u16*   Wkb   = (u16*)(ws + 52428800);
    u16*   Wvb   = (u16*)(ws + 54525952);
    u16*   Wob   = (u16*)(ws + 56623104);
    u16*   Apk   = (u16*)(ws + 58720256);       // 3 x 16384 u16 packed A frags
    int*   flags = (int*)(ws + 59113472);
    u16*   Xbuf  = qb16;

    PrepArgs pa;
    pa.csrc[0] = q;  pa.csrc[1] = k;  pa.csrc[2] = v;
    pa.csrc[3] = Wq; pa.csrc[4] = Wk; pa.csrc[5] = Wv; pa.csrc[6] = Wo;
    pa.cdst[0] = qb16; pa.cdst[1] = kb16; pa.cdst[2] = vb16;
    pa.cdst[3] = Wqb;  pa.cdst[4] = Wkb;  pa.cdst[5] = Wvb; pa.cdst[6] = Wob;
    pa.A[0] = Aq; pa.A[1] = Ak; pa.A[2] = Av;
    pa.apk[0] = Apk; pa.apk[1] = Apk + 16384; pa.apk[2] = Apk + 32768;
    pa.mask = mask; pa.flags = flags;
    prep_kernel<<<dim3(1539), dim3(256), 0, stream>>>(pa);

    const float QSCALE = 0.1803368801f;   // 0.125 * log2(e)
    GemmArgs g1;
    g1.p[0] = GemmPtrs{qb16, Wqb, bq, Apk,         Bq, (void*)QKV,             0, QSCALE};
    g1.p[1] = GemmPtrs{kb16, Wkb, bk, Apk + 16384, Bk, (void*)(QKV + 4194304), 0, 1.0f};
    g1.p[2] = GemmPtrs{vb16, Wvb, bv, Apk + 32768, Bv, (void*)(QKV + 8388608), 1, 1.0f};
    gemm_kernel<4, 4, 1><<<dim3(256, 1, 3), dim3(256), 0, stream>>>(g1);

    attn_kernel<<<dim3(1024), dim3(256), 0, stream>>>(QKV, mask, flags, Xbuf);

    GemmArgs g2;
    g2.p[0] = GemmPtrs{Xbuf, Wob, bo, nullptr, nullptr, d_out, 0, 1.0f};
    g2.p[1] = g2.p[0];
    g2.p[2] = g2.p[0];
    gemm_kernel<2, 4, 0><<<dim3(512, 1, 1), dim3(256), 0, stream>>>(g2);
}